// Round 12
// baseline (187.494 us; speedup 1.0000x reference)
//
#include <hip/hip_runtime.h>

typedef __bf16 bf16;
typedef __attribute__((ext_vector_type(2))) __bf16 bf16x2;
typedef __attribute__((ext_vector_type(4))) __bf16 bf16x4;
typedef __attribute__((ext_vector_type(8))) __bf16 bf16x8;
typedef __attribute__((ext_vector_type(4))) float f32x4;
typedef __attribute__((ext_vector_type(16))) float f32x16;

#define B_ 4
#define S_ 2048
#define H_ 16
#define D_ 64
#define E_ 1024

__device__ __forceinline__ int imin(int a, int b) { return a < b ? a : b; }
__device__ __forceinline__ int imax(int a, int b) { return a > b ? a : b; }

__device__ __forceinline__ void gload_lds16(const void* g, void* l) {
  __builtin_amdgcn_global_load_lds(
      (const __attribute__((address_space(1))) void*)g,
      (__attribute__((address_space(3))) void*)l, 16, 0, 0);
}

// ------ fused f32 -> bf16 convert for x (4096 blk), Wqkv (1536), Wout (512) --
__global__ __launch_bounds__(256) void cvt3_kernel(
    const float* __restrict__ x, bf16* __restrict__ xb,
    const float* __restrict__ wqkv, bf16* __restrict__ wqkvb,
    const float* __restrict__ wout, bf16* __restrict__ woutb) {
  const int bid = blockIdx.x;
  const float* in;
  bf16* out;
  int idx;
  if (bid < 4096) { in = x; out = xb; idx = bid; }
  else if (bid < 5632) { in = wqkv; out = wqkvb; idx = bid - 4096; }
  else { in = wout; out = woutb; idx = bid - 5632; }
  const int i = (idx * 256 + threadIdx.x) * 8;
  float4 v0 = *(const float4*)(in + i);
  float4 v1 = *(const float4*)(in + i + 4);
  bf16x8 o;
  o[0] = (bf16)v0.x; o[1] = (bf16)v0.y; o[2] = (bf16)v0.z; o[3] = (bf16)v0.w;
  o[4] = (bf16)v1.x; o[5] = (bf16)v1.y; o[6] = (bf16)v1.z; o[7] = (bf16)v1.w;
  *(bf16x8*)(out + i) = o;
}

// ---- NT bf16 GEMM: m201-template port. 256x256 block, 8 waves (2Mx4N),
// per-wave 128x64, BK=64, 2-buf LDS (128KB), 8 phases per 2 K-tiles.
// Phase = {ds_read subtile (ops held in regs), stage 1 half-tile, barrier,
// lgkmcnt(0), sched_barrier, setprio(1), 16 MFMA quadrant, setprio(0),
// [vmcnt(0) at K-tile boundary], barrier}. Swizzle: 3-bit granule XOR
// (measured 0 conflicts on this read pattern), both-sides.
__global__ __launch_bounds__(512, 1) void gemm8(
    const bf16* __restrict__ A, const bf16* __restrict__ Bm,
    int K, int mode, int N,
    bf16* __restrict__ qd, bf16* __restrict__ kd, bf16* __restrict__ vtd,
    float* __restrict__ outf) {
  __shared__ __align__(16) bf16 As[2][256 * 64];
  __shared__ __align__(16) bf16 Bs[2][256 * 64];
  const int tid = threadIdx.x;
  const int wave = tid >> 6, lane = tid & 63;
  const int l15 = lane & 15, l4 = lane >> 4;
  const int wm = (wave >> 2) * 128;  // 2 m-groups of 128
  const int wn = (wave & 3) * 64;    // 4 n-groups of 64

  const int nwg = gridDim.x * gridDim.y;
  const int fid = blockIdx.y * gridDim.x + blockIdx.x;
  const int chunk = nwg >> 3;  // nwg % 8 == 0
  const int swz = (fid & 7) * chunk + (fid >> 3);
  const int tn = swz % gridDim.x;
  const int tm = swz / gridDim.x;

  const bf16* Abase = A + (size_t)tm * 256 * K;
  const bf16* Bbase = Bm + (size_t)tn * 256 * K;

  f32x4 acc[8][4];
#pragma unroll
  for (int i = 0; i < 8; ++i)
#pragma unroll
    for (int j = 0; j < 4; ++j)
#pragma unroll
      for (int r = 0; r < 4; ++r) acc[i][j][r] = 0.f;

  const int NT = K >> 6;  // 16 K-tiles
  const int NI = K >> 7;  // 8 iterations (2 K-tiles each)

#define STG8(lds, gb, half, k0)                                                \
  {                                                                            \
    _Pragma("unroll") for (int ld = 0; ld < 2; ++ld) {                         \
      const int idx = ld * 512 + tid;                                          \
      const int row = (half) * 128 + (idx >> 3);                               \
      const int gs = (idx & 7) ^ (row & 7);                                    \
      gload_lds16((gb) + (size_t)row * K + (k0) + gs * 8,                      \
                  (lds) + (half) * 8192 + idx * 8);                            \
    }                                                                          \
  }
#define RD(ldsbuf, r, ks)                                                      \
  (*(const bf16x8*)((ldsbuf) + (r) * 64 + ((((ks) * 4 + l4) ^ ((r) & 7)) * 8)))

  // prologue: tile 0 -> buf0
  STG8(As[0], Abase, 0, 0); STG8(As[0], Abase, 1, 0);
  STG8(Bs[0], Bbase, 0, 0); STG8(Bs[0], Bbase, 1, 0);
  asm volatile("s_waitcnt vmcnt(0)" ::: "memory");
  __builtin_amdgcn_s_barrier();

  bf16x8 af[4][2], bfv[4][2];

  for (int it = 0; it < NI; ++it) {
    const int kA = (2 * it + 1) << 6;                   // tile for buf1
    const int t2 = 2 * it + 2;
    const int kB = ((t2 < NT) ? t2 : NT - 1) << 6;      // next tile for buf0

#pragma unroll
    for (int half = 0; half < 2; ++half) {
      const bf16* Ap = As[half];
      const bf16* Bp = Bs[half];
      bf16* Asd = As[half ^ 1];
      bf16* Bsd = Bs[half ^ 1];
      const int kS = half ? kB : kA;

      // ---- phase 1 (quadrant m0,n0): read A-m0 + all B; stage A-h0 ----
#pragma unroll
      for (int i = 0; i < 4; ++i) {
        const int ra = wm + i * 16 + l15;
        af[i][0] = RD(Ap, ra, 0);
        af[i][1] = RD(Ap, ra, 1);
      }
#pragma unroll
      for (int c = 0; c < 4; ++c) {
        const int rb = wn + (c >> 1) * 32 + (c & 1) * 16 + l15;
        bfv[c][0] = RD(Bp, rb, 0);
        bfv[c][1] = RD(Bp, rb, 1);
      }
      STG8(Asd, Abase, 0, kS);
      __builtin_amdgcn_s_barrier();
      asm volatile("s_waitcnt lgkmcnt(0)" ::: "memory");
      __builtin_amdgcn_sched_barrier(0);
      __builtin_amdgcn_s_setprio(1);
#pragma unroll
      for (int ks = 0; ks < 2; ++ks)
#pragma unroll
        for (int i = 0; i < 4; ++i)
#pragma unroll
          for (int j = 0; j < 2; ++j)
            acc[i][j] = __builtin_amdgcn_mfma_f32_16x16x32_bf16(
                af[i][ks], bfv[j][ks], acc[i][j], 0, 0, 0);
      __builtin_amdgcn_s_setprio(0);
      __builtin_amdgcn_s_barrier();

      // ---- phase 2 (m0,n1): no reads; stage A-h1 ----
      STG8(Asd, Abase, 1, kS);
      __builtin_amdgcn_s_barrier();
      __builtin_amdgcn_s_setprio(1);
#pragma unroll
      for (int ks = 0; ks < 2; ++ks)
#pragma unroll
        for (int i = 0; i < 4; ++i)
#pragma unroll
          for (int j = 0; j < 2; ++j)
            acc[i][2 + j] = __builtin_amdgcn_mfma_f32_16x16x32_bf16(
                af[i][ks], bfv[2 + j][ks], acc[i][2 + j], 0, 0, 0);
      __builtin_amdgcn_s_setprio(0);
      __builtin_amdgcn_s_barrier();

      // ---- phase 3 (m1,n0): read A-m1; stage B-h0 ----
#pragma unroll
      for (int i = 0; i < 4; ++i) {
        const int ra = wm + 64 + i * 16 + l15;
        af[i][0] = RD(Ap, ra, 0);
        af[i][1] = RD(Ap, ra, 1);
      }
      STG8(Bsd, Bbase, 0, kS);
      __builtin_amdgcn_s_barrier();
      asm volatile("s_waitcnt lgkmcnt(0)" ::: "memory");
      __builtin_amdgcn_sched_barrier(0);
      __builtin_amdgcn_s_setprio(1);
#pragma unroll
      for (int ks = 0; ks < 2; ++ks)
#pragma unroll
        for (int i = 0; i < 4; ++i)
#pragma unroll
          for (int j = 0; j < 2; ++j)
            acc[4 + i][j] = __builtin_amdgcn_mfma_f32_16x16x32_bf16(
                af[i][ks], bfv[j][ks], acc[4 + i][j], 0, 0, 0);
      __builtin_amdgcn_s_setprio(0);
      __builtin_amdgcn_s_barrier();

      // ---- phase 4 (m1,n1): no reads; stage B-h1; K-tile boundary drain ----
      STG8(Bsd, Bbase, 1, kS);
      __builtin_amdgcn_s_barrier();
      __builtin_amdgcn_s_setprio(1);
#pragma unroll
      for (int ks = 0; ks < 2; ++ks)
#pragma unroll
        for (int i = 0; i < 4; ++i)
#pragma unroll
          for (int j = 0; j < 2; ++j)
            acc[4 + i][2 + j] = __builtin_amdgcn_mfma_f32_16x16x32_bf16(
                af[i][ks], bfv[2 + j][ks], acc[4 + i][2 + j], 0, 0, 0);
      __builtin_amdgcn_s_setprio(0);
      asm volatile("s_waitcnt vmcnt(0)" ::: "memory");
      __builtin_amdgcn_s_barrier();
    }
  }
#undef STG8
#undef RD

  // ---- epilogue ----
  if (mode == 0) {
#pragma unroll
    for (int ms = 0; ms < 2; ++ms)
#pragma unroll
      for (int mi = 0; mi < 4; ++mi) {
        const int m0 = tm * 256 + wm + ms * 64 + mi * 16 + l4 * 4;
        const int b = m0 >> 11, s = m0 & (S_ - 1);
#pragma unroll
        for (int nc = 0; nc < 4; ++nc) {
          const int n = tn * 256 + wn + (nc >> 1) * 32 + (nc & 1) * 16 + l15;
          const int which = n >> 10;
          const int hn = n & 1023;
          const int h = hn >> 6, d = hn & 63;
          const f32x4 av = acc[ms * 4 + mi][nc];
          if (which == 0) {
#pragma unroll
            for (int r = 0; r < 4; ++r)
              qd[((size_t)(b * H_ + h) * S_ + (s + r)) * D_ + d] =
                  (bf16)(av[r] * 0.125f);
          } else if (which == 1) {
#pragma unroll
            for (int r = 0; r < 4; ++r)
              kd[((size_t)(b * H_ + h) * S_ + (s + r)) * D_ + d] = (bf16)av[r];
          } else {
            bf16x4 pv;
#pragma unroll
            for (int r = 0; r < 4; ++r) pv[r] = (bf16)av[r];
            *(bf16x4*)(vtd + ((size_t)(b * H_ + h) * D_ + d) * S_ + s) = pv;
          }
        }
      }
  } else {
#pragma unroll
    for (int ms = 0; ms < 2; ++ms)
#pragma unroll
      for (int mi = 0; mi < 4; ++mi) {
        const int m0 = tm * 256 + wm + ms * 64 + mi * 16 + l4 * 4;
#pragma unroll
        for (int nc = 0; nc < 4; ++nc) {
          const int n = tn * 256 + wn + (nc >> 1) * 32 + (nc & 1) * 16 + l15;
#pragma unroll
          for (int r = 0; r < 4; ++r)
            outf[(size_t)(m0 + r) * N + n] = acc[ms * 4 + mi][nc][r];
        }
      }
  }
}

// ------- mean of v over all S: 256 blocks = 64 bh x 4 d-quarters ----------
__global__ __launch_bounds__(256) void meanv_kernel(const bf16* __restrict__ vt,
                                                    float* __restrict__ meanv) {
  const int bh = blockIdx.x >> 2, dq = blockIdx.x & 3;
  const int tid = threadIdx.x;
  const int dl = tid >> 4;
  const int sl = tid & 15;
  const int d = dq * 16 + dl;
  const bf16* row = vt + ((size_t)bh * D_ + d) * S_;
  float s = 0.f;
#pragma unroll
  for (int it = 0; it < 16; ++it) {
    bf16x8 v = *(const bf16x8*)(row + it * 128 + sl * 8);
#pragma unroll
    for (int j = 0; j < 8; ++j) s += (float)v[j];
  }
#pragma unroll
  for (int m = 1; m < 16; m <<= 1) s += __shfl_xor(s, m, 64);
  if (sl == 0) meanv[(size_t)bh * D_ + d] = s * (1.0f / (float)S_);
}

// -------- flash attention (m214-style): 4 waves x 32 q-rows, KVBLK=64 LDS --
__device__ __forceinline__ int pk2(float a, float b) {
  union { bf16x2 h; int i; } u;
  u.h[0] = (bf16)a; u.h[1] = (bf16)b;
  return u.i;
}

__global__ __launch_bounds__(256) void attn_kernel(
    const bf16* __restrict__ q, const bf16* __restrict__ k,
    const bf16* __restrict__ vt, const float* __restrict__ meanv,
    const int* __restrict__ seq_lengths, const int* __restrict__ wlp,
    const int* __restrict__ wrp, bf16* __restrict__ attn_out) {
  __shared__ __align__(16) bf16 Ks[2][64 * 64];
  __shared__ __align__(16) bf16 Vs[2][64 * 64];
  const int tid = threadIdx.x, wave = tid >> 6, lane = tid & 63;
  const int l31 = lane & 31, l5 = lane >> 5;
  const int bid0 = blockIdx.x;
  const int bid = (bid0 & 7) * 128 + (bid0 >> 3);
  const int bh = bid >> 4;
  const int g = bid & 15;
  const int b = bh >> 4, h = bh & 15;
  const int q0b = g * 128;
  const int q0w = q0b + wave * 32;
  const int seq_len = seq_lengths[b];
  const int wl = wlp[0], wr = wrp[0];

  const bf16* qbase = q + (size_t)bh * S_ * D_;
  const bf16* kbase = k + (size_t)bh * S_ * D_;
  const bf16* vtb = vt + (size_t)bh * D_ * S_;

  bf16x8 qa[4];
#pragma unroll
  for (int dg = 0; dg < 4; ++dg)
    qa[dg] = *(const bf16x8*)(qbase + (size_t)(q0w + l31) * D_ + dg * 16 + l5 * 8);

  const int hi_blk = (wr >= 0) ? imin(q0b + 127 + wr, S_ - 1) : (S_ - 1);
  const int end_blk = imin(hi_blk + 1, seq_len);
  const int lo_blk = (wl >= 0) ? imax(0, q0b - wl) : 0;
  const int beg_blk = lo_blk & ~63;
  const int ntb = (end_blk > beg_blk) ? ((end_blk - beg_blk + 63) >> 6) : 0;

  const int w_hi = (wr >= 0) ? (q0w + 31 + wr) : (S_ - 1);
  const int w_end = imin(w_hi + 1, seq_len);
  const int w_lo = (wl >= 0) ? imax(0, q0w - wl) : 0;

  f32x16 o0, o1;
#pragma unroll
  for (int r = 0; r < 16; ++r) { o0[r] = 0.f; o1[r] = 0.f; }
  float mrun = -1e30f, lrun = 0.f;

#define STAGE(bufb, kt0)                                                       \
  {                                                                            \
    _Pragma("unroll") for (int ld = 0; ld < 2; ++ld) {                         \
      const int idx = ld * 256 + tid;                                          \
      const int row = idx >> 3, gg = idx & 7;                                  \
      const int gs = gg ^ (row & 7);                                           \
      const int krow = imin((kt0) + row, S_ - 1);                              \
      gload_lds16(kbase + (size_t)krow * 64 + gs * 8, Ks[bufb] + idx * 8);     \
      const int vcol = imin((kt0) + gs * 8, S_ - 8);                           \
      gload_lds16(vtb + (size_t)row * S_ + vcol, Vs[bufb] + idx * 8);          \
    }                                                                          \
  }
#define LDS_K(bufb, row, gran)                                                 \
  (*(const bf16x8*)((const char*)(Ks[bufb]) + (row) * 128 +                    \
                    (((gran) ^ ((row) & 7)) << 4)))
#define LDS_V(bufb, row, gran)                                                 \
  (*(const bf16x8*)((const char*)(Vs[bufb]) + (row) * 128 +                    \
                    (((gran) ^ ((row) & 7)) << 4)))

  if (ntb > 0) STAGE(0, beg_blk);
  __syncthreads();

  for (int t = 0; t < ntb; ++t) {
    const int kt = beg_blk + t * 64;
    if (t + 1 < ntb) STAGE((t + 1) & 1, kt + 64);

    const bool active = (kt < w_end) && (kt + 63 >= w_lo);
    if (active) {
      const int bufb = t & 1;
      f32x16 sf0, sf1;
#pragma unroll
      for (int r = 0; r < 16; ++r) { sf0[r] = 0.f; sf1[r] = 0.f; }
#pragma unroll
      for (int dg = 0; dg < 4; ++dg) {
        bf16x8 kb0 = LDS_K(bufb, l31, dg * 2 + l5);
        bf16x8 kb1 = LDS_K(bufb, 32 + l31, dg * 2 + l5);
        sf0 = __builtin_amdgcn_mfma_f32_32x32x16_bf16(kb0, qa[dg], sf0, 0, 0, 0);
        sf1 = __builtin_amdgcn_mfma_f32_32x32x16_bf16(kb1, qa[dg], sf1, 0, 0, 0);
      }

      bool allv = (kt + 63 < seq_len);
      if (wr >= 0) allv = allv && (kt + 63 <= q0w + wr);
      if (wl >= 0) allv = allv && (kt >= q0w + 31 - wl);
      if (!allv) {
        const int qrow = q0w + l31;
#pragma unroll
        for (int hh = 0; hh < 2; ++hh)
#pragma unroll
          for (int r = 0; r < 16; ++r) {
            const int key = kt + hh * 32 + (r & 3) + 8 * (r >> 2) + 4 * l5;
            bool valid = (key < seq_len);
            if (wr >= 0) valid = valid && (key <= qrow + wr);
            if (wl >= 0) valid = valid && (key >= qrow - wl);
            if (hh == 0) sf0[r] = valid ? sf0[r] : -1e30f;
            else sf1[r] = valid ? sf1[r] : -1e30f;
          }
      }
      float tmax = -1e30f;
#pragma unroll
      for (int r = 0; r < 16; ++r) {
        tmax = fmaxf(tmax, sf0[r]);
        tmax = fmaxf(tmax, sf1[r]);
      }
      tmax = fmaxf(tmax, __shfl_xor(tmax, 32, 64));

      if (!__all(tmax <= mrun + 8.0f)) {
        const float mnew = fmaxf(mrun, tmax);
        const float corr = __expf(mrun - mnew);
        mrun = mnew;
        lrun *= corr;
#pragma unroll
        for (int r = 0; r < 16; ++r) { o0[r] *= corr; o1[r] *= corr; }
      }

      float lsum = 0.f;
#pragma unroll
      for (int r = 0; r < 16; ++r) {
        const float e0 = (sf0[r] <= -1e29f) ? 0.f : __expf(sf0[r] - mrun);
        const float e1 = (sf1[r] <= -1e29f) ? 0.f : __expf(sf1[r] - mrun);
        sf0[r] = e0; sf1[r] = e1;
        lsum += e0 + e1;
      }
      lsum += __shfl_xor(lsum, 32, 64);
      lrun += lsum;

      bf16x8 pb[4];
#pragma unroll
      for (int kg = 0; kg < 4; ++kg) {
        const int base = (kg & 1) * 8;
        float p0, p1, p2, p3, p4, p5, p6, p7;
        if (kg < 2) {
          p0 = sf0[base + 0]; p1 = sf0[base + 1]; p2 = sf0[base + 2];
          p3 = sf0[base + 3]; p4 = sf0[base + 4]; p5 = sf0[base + 5];
          p6 = sf0[base + 6]; p7 = sf0[base + 7];
        } else {
          p0 = sf1[base + 0]; p1 = sf1[base + 1]; p2 = sf1[base + 2];
          p3 = sf1[base + 3]; p4 = sf1[base + 4]; p5 = sf1[base + 5];
          p6 = sf1[base + 6]; p7 = sf1[base + 7];
        }
        const int w0 = pk2(p0, p1);
        const int w1 = pk2(p2, p3);
        const int w2 = pk2(p4, p5);
        const int w3 = pk2(p6, p7);
        auto r02 = __builtin_amdgcn_permlane32_swap(w0, w2, false, false);
        auto r13 = __builtin_amdgcn_permlane32_swap(w1, w3, false, false);
        union { int i[4]; bf16x8 v; } u;
        u.i[0] = r02[0]; u.i[1] = r13[0]; u.i[2] = r02[1]; u.i[3] = r13[1];
        pb[kg] = u.v;
      }

#pragma unroll
      for (int kg = 0; kg < 4; ++kg) {
        bf16x8 va0 = LDS_V(bufb, l31, kg * 2 + l5);
        bf16x8 va1 = LDS_V(bufb, 32 + l31, kg * 2 + l5);
        o0 = __builtin_amdgcn_mfma_f32_32x32x16_bf16(va0, pb[kg], o0, 0, 0, 0);
        o1 = __builtin_amdgcn_mfma_f32_32x32x16_bf16(va1, pb[kg], o1, 0, 0, 0);
      }
    }
    __syncthreads();
  }
#undef STAGE
#undef LDS_K
#undef LDS_V

  const int qrow = q0w + l31;
  bf16* outp = attn_out + ((size_t)(b * S_ + qrow)) * E_ + h * 64;
  if (lrun > 0.f) {
    const float inv = 1.0f / lrun;
#pragma unroll
    for (int dg2 = 0; dg2 < 2; ++dg2) {
      const f32x16& o = dg2 ? o1 : o0;
#pragma unroll
      for (int rg = 0; rg < 4; ++rg) {
        const int d0 = dg2 * 32 + 8 * rg + 4 * l5;
        bf16x4 ov;
#pragma unroll
        for (int j = 0; j < 4; ++j) ov[j] = (bf16)(o[rg * 4 + j] * inv);
        *(bf16x4*)(outp + d0) = ov;
      }
    }
  } else {
    const float* mv = meanv + (size_t)bh * D_;
#pragma unroll
    for (int dg2 = 0; dg2 < 2; ++dg2)
#pragma unroll
      for (int rg = 0; rg < 4; ++rg) {
        const int d0 = dg2 * 32 + 8 * rg + 4 * l5;
        bf16x4 ov;
#pragma unroll
        for (int j = 0; j < 4; ++j) ov[j] = (bf16)mv[d0 + j];
        *(bf16x4*)(outp + d0) = ov;
      }
  }
}

// ---------------- launch ----------------
extern "C" void kernel_launch(void* const* d_in, const int* in_sizes, int n_in,
                              void* d_out, int out_size, void* d_ws, size_t ws_size,
                              hipStream_t stream) {
  const float* x = (const float*)d_in[0];
  const float* Wqkv = (const float*)d_in[1];
  const float* Wout = (const float*)d_in[2];
  const int* seq_lengths = (const int*)d_in[3];
  const int* wl = (const int*)d_in[4];
  const int* wr = (const int*)d_in[5];
  float* out = (float*)d_out;

  char* ws = (char*)d_ws;
  bf16* xb = (bf16*)ws;      ws += (size_t)8192 * 1024 * 2;
  bf16* wqkvb = (bf16*)ws;   ws += (size_t)3072 * 1024 * 2;
  bf16* woutb = (bf16*)ws;   ws += (size_t)1024 * 1024 * 2;
  bf16* qd = (bf16*)ws;      ws += (size_t)B_ * H_ * S_ * D_ * 2;
  bf16* kd = (bf16*)ws;      ws += (size_t)B_ * H_ * S_ * D_ * 2;
  bf16* vtd = (bf16*)ws;     ws += (size_t)B_ * H_ * S_ * D_ * 2;
  bf16* attn = (bf16*)ws;    ws += (size_t)8192 * 1024 * 2;
  float* meanv = (float*)ws; ws += (size_t)B_ * H_ * D_ * 4;

  cvt3_kernel<<<6144, 256, 0, stream>>>(x, xb, Wqkv, wqkvb, Wout, woutb);

  gemm8<<<dim3(12, 32), 512, 0, stream>>>(xb, wqkvb, 1024, 0, 3072,
                                          qd, kd, vtd, nullptr);
  meanv_kernel<<<256, 256, 0, stream>>>(vtd, meanv);
  attn_kernel<<<1024, 256, 0, stream>>>(qd, kd, vtd, meanv, seq_lengths, wl, wr,
                                        attn);
  gemm8<<<dim3(4, 32), 512, 0, stream>>>(attn, woutb, 1024, 1, 1024,
                                         nullptr, nullptr, nullptr, out);
}